// Round 4
// baseline (408.828 us; speedup 1.0000x reference)
//
#include <hip/hip_runtime.h>
#include <math.h>

// Problem constants
#define NN   4096   // total nodes
#define HH   256    // hidden
#define NEC  119    // element classes
#define NBC  5      // bond classes
#define NMOL 64     // molecules
#define MAT  64     // atoms per molecule

// output layout (float elements)
#define OFF_ATOM   0
#define SZ_ATOM    (4096*119)          // 487424
#define OFF_BOND   487424
#define SZ_BOND    (258048*5)          // 1290240
#define OFF_VALM   (487424+1290240)    // 1777664
#define SZ_VALM    (4096*4096)         // 16777216
#define OFF_ADJ    (1777664+16777216)  // 18554880

typedef short  bf16x8 __attribute__((ext_vector_type(8)));
typedef float  f32x4  __attribute__((ext_vector_type(4)));

// Branchless gelu: 0.5x(1+erf(x/sqrt2)), erf via A&S 7.1.26 (|err|<=1.5e-7).
// 1 rcp + 1 exp (quarter-rate) + ~12 full-rate ops; no divergent branches.
__device__ __forceinline__ float gelu_f(float x) {
    float z = fabsf(x) * 0.70710678118654752f;
    float t = __builtin_amdgcn_rcpf(fmaf(0.3275911f, z, 1.0f));
    float p = t * fmaf(t, fmaf(t, fmaf(t, fmaf(t, 1.061405429f, -1.453152027f),
                                       1.421413741f), -0.284496736f), 0.254829592f);
    float er = fmaf(-p, __expf(-z * z), 1.0f);   // erf(|x|/sqrt2)
    float s = copysignf(er, x);
    return 0.5f * x * (1.f + s);
}
__device__ __forceinline__ unsigned short f2bf(float x) {
    unsigned int u = __float_as_uint(x);
    unsigned int r = (u + 0x7fffu + ((u >> 16) & 1u)) >> 16;
    return (unsigned short)r;
}

// ---------------------------------------------------------------------------
// K1: fused atom MLP + valency MLP, 8 nodes per block (512 blocks).
//  atom: h[8,256] -> logits[8,119] (+softmax probs into LDS, argmax -> ma,rad)
//  val:  concat(h,probs)[8,375] -> softplus -> val[8]
// ---------------------------------------------------------------------------
__global__ __launch_bounds__(256) void k_av(
    const float* __restrict__ h,
    const float* __restrict__ aW1, const float* __restrict__ ab1,
    const float* __restrict__ ag,  const float* __restrict__ abn,
    const float* __restrict__ aW2, const float* __restrict__ ab2,
    const float* __restrict__ aW3, const float* __restrict__ ab3,
    const float* __restrict__ maxv, const float* __restrict__ covr,
    const float* __restrict__ vW1, const float* __restrict__ vb1,
    const float* __restrict__ vg,  const float* __restrict__ vbn,
    const float* __restrict__ vW2, const float* __restrict__ vb2,
    const float* __restrict__ vW3, const float* __restrict__ vb3,
    float* __restrict__ logits_out,
    float* __restrict__ ma, float* __restrict__ rad, float* __restrict__ val)
{
    __shared__ float hs[8][376];     // h (0..255) + probs (256..374) + pad
    __shared__ float z1[8][256];
    __shared__ float z2[8][128];
    __shared__ float llog[8][120];
    __shared__ float redbuf[8][2];

    const int t  = threadIdx.x;
    const int n0 = blockIdx.x * 8;
    const int wv = t >> 6, ln = t & 63;

    for (int idx = t; idx < 8 * 256; idx += 256) {
        int r = idx >> 8, cc = idx & 255;
        hs[r][cc] = h[(size_t)(n0 + r) * 256 + cc];
    }
    if (t < 8) hs[t][375] = 0.f;
    __syncthreads();

    // ---- atom layer1 (256->256): thread owns col c ----
    {
        const int c = t;
        float b1 = ab1[c];
        float acc[8];
        #pragma unroll
        for (int r = 0; r < 8; ++r) acc[r] = b1;
        for (int k4 = 0; k4 < 64; ++k4) {
            const int k = k4 * 4;
            float w0 = aW1[(k + 0) * 256 + c];
            float w1 = aW1[(k + 1) * 256 + c];
            float w2 = aW1[(k + 2) * 256 + c];
            float w3 = aW1[(k + 3) * 256 + c];
            #pragma unroll
            for (int r = 0; r < 8; ++r) {
                float4 hv = *(const float4*)&hs[r][k];
                acc[r] = fmaf(hv.x, w0, acc[r]);
                acc[r] = fmaf(hv.y, w1, acc[r]);
                acc[r] = fmaf(hv.z, w2, acc[r]);
                acc[r] = fmaf(hv.w, w3, acc[r]);
            }
        }
        #pragma unroll
        for (int r = 0; r < 8; ++r) z1[r][c] = gelu_f(acc[r]);
    }
    __syncthreads();

    // ---- atom LN stats: wave wv owns rows wv*2, wv*2+1 ----
    for (int rr = 0; rr < 2; ++rr) {
        const int r = wv * 2 + rr;
        float s = 0.f, s2 = 0.f;
        #pragma unroll
        for (int q = 0; q < 4; ++q) {
            float v = z1[r][ln + q * 64];
            s += v; s2 = fmaf(v, v, s2);
        }
        #pragma unroll
        for (int m = 32; m >= 1; m >>= 1) {
            s  += __shfl_xor(s,  m, 64);
            s2 += __shfl_xor(s2, m, 64);
        }
        if (ln == 0) {
            float mu  = s * (1.f / 256.f);
            float var = s2 * (1.f / 256.f) - mu * mu;
            redbuf[r][0] = mu;
            redbuf[r][1] = rsqrtf(var + 1e-5f);
        }
    }
    __syncthreads();
    {
        const int c = t;
        float g = ag[c], b = abn[c];
        #pragma unroll
        for (int r = 0; r < 8; ++r)
            z1[r][c] = (z1[r][c] - redbuf[r][0]) * redbuf[r][1] * g + b;
    }
    __syncthreads();

    // ---- atom layer2 (256->128), k-split halves ----
    {
        const int c2 = t & 127, kh = t >> 7;
        float acc2[8];
        #pragma unroll
        for (int r = 0; r < 8; ++r) acc2[r] = 0.f;
        const int kb = kh * 128;
        for (int k4 = 0; k4 < 32; ++k4) {
            const int k = kb + k4 * 4;
            float w0 = aW2[(k + 0) * 128 + c2];
            float w1 = aW2[(k + 1) * 128 + c2];
            float w2 = aW2[(k + 2) * 128 + c2];
            float w3 = aW2[(k + 3) * 128 + c2];
            #pragma unroll
            for (int r = 0; r < 8; ++r) {
                float4 zv = *(const float4*)&z1[r][k];
                acc2[r] = fmaf(zv.x, w0, acc2[r]);
                acc2[r] = fmaf(zv.y, w1, acc2[r]);
                acc2[r] = fmaf(zv.z, w2, acc2[r]);
                acc2[r] = fmaf(zv.w, w3, acc2[r]);
            }
        }
        if (kh == 1) {
            #pragma unroll
            for (int r = 0; r < 8; ++r) z2[r][c2] = acc2[r];
        }
        __syncthreads();
        if (kh == 0) {
            float b2 = ab2[c2];
            #pragma unroll
            for (int r = 0; r < 8; ++r)
                z2[r][c2] = gelu_f(acc2[r] + z2[r][c2] + b2);
        }
    }
    __syncthreads();

    // ---- atom layer3 (128->119) ----
    if (t < NEC) {
        const int c = t;
        float b3 = ab3[c];
        float acc3[8];
        #pragma unroll
        for (int r = 0; r < 8; ++r) acc3[r] = b3;
        for (int k4 = 0; k4 < 32; ++k4) {
            const int k = k4 * 4;
            float w0 = aW3[(k + 0) * NEC + c];
            float w1 = aW3[(k + 1) * NEC + c];
            float w2 = aW3[(k + 2) * NEC + c];
            float w3 = aW3[(k + 3) * NEC + c];
            #pragma unroll
            for (int r = 0; r < 8; ++r) {
                float4 zv = *(const float4*)&z2[r][k];
                acc3[r] = fmaf(zv.x, w0, acc3[r]);
                acc3[r] = fmaf(zv.y, w1, acc3[r]);
                acc3[r] = fmaf(zv.z, w2, acc3[r]);
                acc3[r] = fmaf(zv.w, w3, acc3[r]);
            }
        }
        #pragma unroll
        for (int r = 0; r < 8; ++r) {
            llog[r][c] = acc3[r];
            logits_out[(size_t)(n0 + r) * NEC + c] = acc3[r];
        }
    }
    __syncthreads();

    // ---- atom softmax + argmax; probs -> hs[r][256+cc] ----
    for (int rr = 0; rr < 2; ++rr) {
        const int r = wv * 2 + rr;
        float v1 = llog[r][ln];
        float v2 = (ln + 64 < NEC) ? llog[r][ln + 64] : -1e30f;
        float mx; int mi;
        if (v2 > v1) { mx = v2; mi = ln + 64; } else { mx = v1; mi = ln; }
        #pragma unroll
        for (int m = 32; m >= 1; m >>= 1) {
            float ov = __shfl_xor(mx, m, 64);
            int   oi = __shfl_xor(mi, m, 64);
            if (ov > mx || (ov == mx && oi < mi)) { mx = ov; mi = oi; }
        }
        float e1 = __expf(v1 - mx);
        float e2 = (ln + 64 < NEC) ? __expf(v2 - mx) : 0.f;
        float s = e1 + e2;
        #pragma unroll
        for (int m = 32; m >= 1; m >>= 1) s += __shfl_xor(s, m, 64);
        float inv = __builtin_amdgcn_rcpf(s);
        hs[r][256 + ln] = e1 * inv;
        if (ln + 64 < NEC) hs[r][256 + ln + 64] = e2 * inv;
        if (ln == 0) {
            ma[n0 + r]  = maxv[mi];
            rad[n0 + r] = covr[mi];
        }
    }
    __syncthreads();

    // ---- valency layer1 (375->256) ----
    {
        const int c = t;
        float b1 = vb1[c];
        float acc[8];
        #pragma unroll
        for (int r = 0; r < 8; ++r) acc[r] = b1;
        for (int k4 = 0; k4 < 94; ++k4) {
            const int k = k4 * 4;
            float w0 = (k + 0 < 375) ? vW1[(k + 0) * 256 + c] : 0.f;
            float w1 = (k + 1 < 375) ? vW1[(k + 1) * 256 + c] : 0.f;
            float w2 = (k + 2 < 375) ? vW1[(k + 2) * 256 + c] : 0.f;
            float w3 = (k + 3 < 375) ? vW1[(k + 3) * 256 + c] : 0.f;
            #pragma unroll
            for (int r = 0; r < 8; ++r) {
                float4 hv = *(const float4*)&hs[r][k];
                acc[r] = fmaf(hv.x, w0, acc[r]);
                acc[r] = fmaf(hv.y, w1, acc[r]);
                acc[r] = fmaf(hv.z, w2, acc[r]);
                acc[r] = fmaf(hv.w, w3, acc[r]);
            }
        }
        #pragma unroll
        for (int r = 0; r < 8; ++r) z1[r][c] = gelu_f(acc[r]);
    }
    __syncthreads();

    // ---- valency LN ----
    for (int rr = 0; rr < 2; ++rr) {
        const int r = wv * 2 + rr;
        float s = 0.f, s2 = 0.f;
        #pragma unroll
        for (int q = 0; q < 4; ++q) {
            float v = z1[r][ln + q * 64];
            s += v; s2 = fmaf(v, v, s2);
        }
        #pragma unroll
        for (int m = 32; m >= 1; m >>= 1) {
            s  += __shfl_xor(s,  m, 64);
            s2 += __shfl_xor(s2, m, 64);
        }
        if (ln == 0) {
            float mu  = s * (1.f / 256.f);
            float var = s2 * (1.f / 256.f) - mu * mu;
            redbuf[r][0] = mu;
            redbuf[r][1] = rsqrtf(var + 1e-5f);
        }
    }
    __syncthreads();
    {
        const int c = t;
        float g = vg[c], b = vbn[c];
        #pragma unroll
        for (int r = 0; r < 8; ++r)
            z1[r][c] = (z1[r][c] - redbuf[r][0]) * redbuf[r][1] * g + b;
    }
    __syncthreads();

    // ---- valency layer2 (256->128) ----
    {
        const int c2 = t & 127, kh = t >> 7;
        float acc2[8];
        #pragma unroll
        for (int r = 0; r < 8; ++r) acc2[r] = 0.f;
        const int kb = kh * 128;
        for (int k4 = 0; k4 < 32; ++k4) {
            const int k = kb + k4 * 4;
            float w0 = vW2[(k + 0) * 128 + c2];
            float w1 = vW2[(k + 1) * 128 + c2];
            float w2 = vW2[(k + 2) * 128 + c2];
            float w3 = vW2[(k + 3) * 128 + c2];
            #pragma unroll
            for (int r = 0; r < 8; ++r) {
                float4 zv = *(const float4*)&z1[r][k];
                acc2[r] = fmaf(zv.x, w0, acc2[r]);
                acc2[r] = fmaf(zv.y, w1, acc2[r]);
                acc2[r] = fmaf(zv.z, w2, acc2[r]);
                acc2[r] = fmaf(zv.w, w3, acc2[r]);
            }
        }
        if (kh == 1) {
            #pragma unroll
            for (int r = 0; r < 8; ++r) z2[r][c2] = acc2[r];
        }
        __syncthreads();
        if (kh == 0) {
            float b2 = vb2[c2];
            #pragma unroll
            for (int r = 0; r < 8; ++r)
                z2[r][c2] = gelu_f(acc2[r] + z2[r][c2] + b2);
        }
    }
    __syncthreads();

    // ---- valency layer3 (128->1) + softplus ----
    for (int rr = 0; rr < 2; ++rr) {
        const int r = wv * 2 + rr;
        float p = fmaf(z2[r][ln], vW3[ln], z2[r][ln + 64] * vW3[ln + 64]);
        #pragma unroll
        for (int m = 32; m >= 1; m >>= 1) p += __shfl_xor(p, m, 64);
        if (ln == 0) {
            float x = p + vb3[0];
            val[n0 + r] = (x > 15.f) ? x : log1pf(expf(x));
        }
    }
}

// ---------------------------------------------------------------------------
// K3: valency_constrained[i,j] = min(val[j], ma[i])   (67 MB write)
// ---------------------------------------------------------------------------
__global__ __launch_bounds__(256) void k_valmat(
    const float* __restrict__ val, const float* __restrict__ ma,
    float* __restrict__ out)
{
    const int i = blockIdx.x;
    const float mi = ma[i];
    const float4* v4 = (const float4*)val;
    float4* o4 = (float4*)(out + (size_t)i * 4096);
    for (int j = threadIdx.x; j < 1024; j += 256) {
        float4 v = v4[j];
        float4 r;
        r.x = fminf(v.x, mi); r.y = fminf(v.y, mi);
        r.z = fminf(v.z, mi); r.w = fminf(v.w, mi);
        o4[j] = r;
    }
}

// ---------------------------------------------------------------------------
// K4: P = h @ bW1[0:256] + bb1 ; Q = h @ bW1[256:512]  (8 rows/block, 512 blk)
//     blocks 0..127 also pre-pack bW2/bW3 into MFMA B-fragments (bf16):
//     lane l supplies B[k=(l>>4)*8+e][col=l&15], e=0..7.
// ---------------------------------------------------------------------------
__global__ __launch_bounds__(256) void k_pq(
    const float* __restrict__ h, const float* __restrict__ bW1,
    const float* __restrict__ bb1,
    const float* __restrict__ bW2, const float* __restrict__ bW3,
    float* __restrict__ P, float* __restrict__ Q,
    short* __restrict__ W2f, short* __restrict__ W3f)
{
    const int t  = threadIdx.x;
    const int n0 = blockIdx.x * 8;

    if (blockIdx.x < 128) {
        const int id = blockIdx.x * 256 + t;
        {   // W2f: [256,128] -> fragments, id < 32768
            const int e = id & 7, l = (id >> 3) & 63, ks = (id >> 9) & 7, ct = (id >> 12) & 7;
            const int k = ks * 32 + (l >> 4) * 8 + e;
            const int col = ct * 16 + (l & 15);
            W2f[id] = (short)f2bf(bW2[k * 128 + col]);
        }
        if (id < 2048) {
            const int e = id & 7, l = (id >> 3) & 63, ks = id >> 9;
            const int k = ks * 32 + (l >> 4) * 8 + e;
            const int col = l & 15;
            W3f[id] = (col < NBC) ? (short)f2bf(bW3[k * NBC + col]) : (short)0;
        }
    }

    __shared__ float hs[8][256];
    for (int idx = t; idx < 8 * 256; idx += 256)
        ((float*)hs)[idx] = h[(size_t)n0 * 256 + idx];
    __syncthreads();

    const int c = t;
    float accp[8], accq[8];
    float b1 = bb1[c];
    #pragma unroll
    for (int r = 0; r < 8; ++r) { accp[r] = b1; accq[r] = 0.f; }
    for (int k4 = 0; k4 < 64; ++k4) {
        const int k = k4 * 4;
        float p0 = bW1[(k + 0) * 256 + c];
        float p1 = bW1[(k + 1) * 256 + c];
        float p2 = bW1[(k + 2) * 256 + c];
        float p3 = bW1[(k + 3) * 256 + c];
        float q0 = bW1[(256 + k + 0) * 256 + c];
        float q1 = bW1[(256 + k + 1) * 256 + c];
        float q2 = bW1[(256 + k + 2) * 256 + c];
        float q3 = bW1[(256 + k + 3) * 256 + c];
        #pragma unroll
        for (int r = 0; r < 8; ++r) {
            float4 hv = *(const float4*)&hs[r][k];
            accp[r] = fmaf(hv.x, p0, accp[r]);
            accp[r] = fmaf(hv.y, p1, accp[r]);
            accp[r] = fmaf(hv.z, p2, accp[r]);
            accp[r] = fmaf(hv.w, p3, accp[r]);
            accq[r] = fmaf(hv.x, q0, accq[r]);
            accq[r] = fmaf(hv.y, q1, accq[r]);
            accq[r] = fmaf(hv.z, q2, accq[r]);
            accq[r] = fmaf(hv.w, q3, accq[r]);
        }
    }
    #pragma unroll
    for (int r = 0; r < 8; ++r) {
        P[(size_t)(n0 + r) * 256 + c] = accp[r];
        Q[(size_t)(n0 + r) * 256 + c] = accq[r];
    }
}

// ---------------------------------------------------------------------------
// K5: bond MLP per (b,i): 64 pairs (j=0..63).
//  Phase A (wave-parallel): layer1 = P[i]+Q[j]+geo@Wg -> gelu -> LN (64-lane
//    butterfly) -> bf16 into Xs, XOR-swizzled.
//  Phase B: MFMA 16x16x32 bf16: Y = Xs @ W2f; barrier; gelu(+bb2) -> Ys
//    (ALIASES Xs — Xs dead after the MFMAs; saves 16 KB LDS -> 4 blocks/CU).
//  Phase B2: MFMA: L[64,16] = Ys @ W3f -> Ls[64][5].
//  Writer: softmax5 -> adjacency (diag=e0), logits+bias -> bond_logits.
// ---------------------------------------------------------------------------
__global__ __launch_bounds__(256) void k_bond(
    const float* __restrict__ pos, const float* __restrict__ rad,
    const float* __restrict__ P, const float* __restrict__ Q,
    const float* __restrict__ bW1,
    const float* __restrict__ bg, const float* __restrict__ bbn,
    const float* __restrict__ bb2,
    const short* __restrict__ W2f, const short* __restrict__ W3f,
    const float* __restrict__ bb3,
    float* __restrict__ bond_logits, float* __restrict__ adjacency)
{
    __shared__ float posr[64][4];
    __shared__ float bb2s[128];
    __shared__ unsigned short Xs[64 * 256];   // bf16; 16B-chunk XOR swizzle by (row&7)
    __shared__ float Ls[64][5];
    unsigned short* Ys = Xs;                  // alias: Xs dead after Phase B MFMAs

    const int t  = threadIdx.x;
    const int bi = blockIdx.x;
    const int b  = bi >> 6, i = bi & 63;
    const int wv = t >> 6, ln = t & 63;
    const int node0 = b * 64;

    if (t < 64) {
        int n = node0 + t;
        posr[t][0] = pos[n * 3 + 0];
        posr[t][1] = pos[n * 3 + 1];
        posr[t][2] = pos[n * 3 + 2];
        posr[t][3] = rad[n];
    }
    if (t >= 128 && t < 256) bb2s[t - 128] = bb2[t - 128];
    __syncthreads();

    // ---- Phase A: layer1 + LN, wave wv owns j in [wv*16, wv*16+16) ----
    {
        const int c0 = ln * 4;                    // lane owns channels c0..c0+3
        const size_t nodei = (size_t)(node0 + i);
        float4 Pi  = *(const float4*)(P + nodei * 256 + c0);
        float4 w0  = *(const float4*)(bW1 + (size_t)512 * 256 + c0);
        float4 w1  = *(const float4*)(bW1 + (size_t)513 * 256 + c0);
        float4 w2  = *(const float4*)(bW1 + (size_t)514 * 256 + c0);
        float4 w3  = *(const float4*)(bW1 + (size_t)515 * 256 + c0);
        float4 gam = *(const float4*)(bg  + c0);
        float4 bet = *(const float4*)(bbn + c0);
        const float xi = posr[i][0], yi = posr[i][1], zi = posr[i][2], ri = posr[i][3];

        for (int jj = 0; jj < 16; ++jj) {
            const int j = wv * 16 + jj;
            float dx = xi - posr[j][0];
            float dy = yi - posr[j][1];
            float dz = zi - posr[j][2];
            float dist = sqrtf(fmaf(dx, dx, fmaf(dy, dy, dz * dz)));
            float expd = ri + posr[j][3];
            float ratio = dist * __builtin_amdgcn_rcpf(expd);
            float close = (dist < 3.f) ? 1.f : 0.f;
            float4 qv = *(const float4*)(Q + (size_t)(node0 + j) * 256 + c0);

            float g0 = Pi.x + qv.x;
            g0 = fmaf(w0.x, dist, g0); g0 = fmaf(w1.x, expd, g0);
            g0 = fmaf(w2.x, ratio, g0); g0 = fmaf(w3.x, close, g0);
            float g1 = Pi.y + qv.y;
            g1 = fmaf(w0.y, dist, g1); g1 = fmaf(w1.y, expd, g1);
            g1 = fmaf(w2.y, ratio, g1); g1 = fmaf(w3.y, close, g1);
            float g2 = Pi.z + qv.z;
            g2 = fmaf(w0.z, dist, g2); g2 = fmaf(w1.z, expd, g2);
            g2 = fmaf(w2.z, ratio, g2); g2 = fmaf(w3.z, close, g2);
            float g3 = Pi.w + qv.w;
            g3 = fmaf(w0.w, dist, g3); g3 = fmaf(w1.w, expd, g3);
            g3 = fmaf(w2.w, ratio, g3); g3 = fmaf(w3.w, close, g3);
            g0 = gelu_f(g0); g1 = gelu_f(g1); g2 = gelu_f(g2); g3 = gelu_f(g3);

            float s  = g0 + g1 + g2 + g3;
            float s2 = fmaf(g0, g0, fmaf(g1, g1, fmaf(g2, g2, g3 * g3)));
            #pragma unroll
            for (int m = 32; m >= 1; m >>= 1) {
                s  += __shfl_xor(s,  m, 64);
                s2 += __shfl_xor(s2, m, 64);
            }
            float mu   = s * (1.f / 256.f);
            float rstd = rsqrtf(s2 * (1.f / 256.f) - mu * mu + 1e-5f);

            ushort4 u;
            u.x = f2bf((g0 - mu) * rstd * gam.x + bet.x);
            u.y = f2bf((g1 - mu) * rstd * gam.y + bet.y);
            u.z = f2bf((g2 - mu) * rstd * gam.z + bet.z);
            u.w = f2bf((g3 - mu) * rstd * gam.w + bet.w);
            // swizzled write: chunk = c0/8, chunk' = chunk ^ (j&7)
            const int chunk = ln >> 1;
            const int off   = j * 512 + ((chunk ^ (j & 7)) << 4) + ((ln & 1) << 3);
            *(ushort4*)((char*)Xs + off) = u;
        }
    }
    __syncthreads();

    // ---- Phase B: Y = Xs @ W2f via MFMA; wave wv owns cols [wv*32, wv*32+32) ----
    {
        const int lrow = ln & 15, lk = ln >> 4;
        f32x4 acc[4][2];
        #pragma unroll
        for (int jt = 0; jt < 4; ++jt)
            #pragma unroll
            for (int c2 = 0; c2 < 2; ++c2)
                acc[jt][c2] = (f32x4){0.f, 0.f, 0.f, 0.f};

        #pragma unroll
        for (int ks = 0; ks < 8; ++ks) {
            bf16x8 bfr0 = *(const bf16x8*)(W2f + (((size_t)(2 * wv + 0) * 8 + ks) * 64 + ln) * 8);
            bf16x8 bfr1 = *(const bf16x8*)(W2f + (((size_t)(2 * wv + 1) * 8 + ks) * 64 + ln) * 8);
            #pragma unroll
            for (int jt = 0; jt < 4; ++jt) {
                const int row   = jt * 16 + lrow;
                const int chunk = ks * 4 + lk;
                const int off   = row * 512 + ((chunk ^ (row & 7)) << 4);
                bf16x8 afr = *(const bf16x8*)((char*)Xs + off);
                acc[jt][0] = __builtin_amdgcn_mfma_f32_16x16x32_bf16(afr, bfr0, acc[jt][0], 0, 0, 0);
                acc[jt][1] = __builtin_amdgcn_mfma_f32_16x16x32_bf16(afr, bfr1, acc[jt][1], 0, 0, 0);
            }
        }
        __syncthreads();   // all waves done reading Xs before Ys (alias) writes

        // epilogue: gelu(Y + bb2) -> Ys (bf16, swizzled)
        #pragma unroll
        for (int jt = 0; jt < 4; ++jt) {
            #pragma unroll
            for (int c2 = 0; c2 < 2; ++c2) {
                const int col = (2 * wv + c2) * 16 + lrow;
                const float bb = bb2s[col];
                #pragma unroll
                for (int r = 0; r < 4; ++r) {
                    const int row = jt * 16 + lk * 4 + r;
                    float y = gelu_f(acc[jt][c2][r] + bb);
                    const int chunk = col >> 3;
                    const int off = row * 256 + ((chunk ^ (row & 7)) << 4) + ((col & 7) << 1);
                    *(unsigned short*)((char*)Ys + off) = f2bf(y);
                }
            }
        }
    }
    __syncthreads();

    // ---- Phase B2: L = Ys @ W3f (pad 16 cols); wave wv owns j-tile wv ----
    {
        const int lrow = ln & 15, lk = ln >> 4;
        f32x4 acc3 = (f32x4){0.f, 0.f, 0.f, 0.f};
        #pragma unroll
        for (int ks = 0; ks < 4; ++ks) {
            bf16x8 bfr = *(const bf16x8*)(W3f + ((size_t)(ks * 64 + ln)) * 8);
            const int row   = wv * 16 + lrow;
            const int chunk = ks * 4 + lk;
            const int off   = row * 256 + ((chunk ^ (row & 7)) << 4);
            bf16x8 afr = *(const bf16x8*)((char*)Ys + off);
            acc3 = __builtin_amdgcn_mfma_f32_16x16x32_bf16(afr, bfr, acc3, 0, 0, 0);
        }
        if (lrow < NBC) {
            #pragma unroll
            for (int r = 0; r < 4; ++r)
                Ls[wv * 16 + lk * 4 + r][lrow] = acc3[r];
        }
    }
    __syncthreads();

    // ---- write adjacency (softmax5, diag=e0) + bond_logits (off-diag) ----
    const size_t adjbase  = (size_t)bi * 64 * 5;
    const size_t bondbase = ((size_t)b * 4032 + (size_t)i * 63) * 5;
    const float b30 = bb3[0], b31 = bb3[1], b32 = bb3[2], b33 = bb3[3], b34 = bb3[4];
    for (int u = t; u < 320; u += 256) {
        const int j = u / 5, o = u - (u / 5) * 5;
        float l0 = Ls[j][0] + b30, l1 = Ls[j][1] + b31, l2 = Ls[j][2] + b32;
        float l3 = Ls[j][3] + b33, l4 = Ls[j][4] + b34;
        float mx = fmaxf(fmaxf(fmaxf(l0, l1), fmaxf(l2, l3)), l4);
        float e0 = __expf(l0 - mx), e1 = __expf(l1 - mx), e2 = __expf(l2 - mx);
        float e3 = __expf(l3 - mx), e4 = __expf(l4 - mx);
        float inv = __builtin_amdgcn_rcpf(e0 + e1 + e2 + e3 + e4);
        float lo = (o == 0) ? l0 : (o == 1) ? l1 : (o == 2) ? l2 : (o == 3) ? l3 : l4;
        float po = ((o == 0) ? e0 : (o == 1) ? e1 : (o == 2) ? e2 : (o == 3) ? e3 : e4) * inv;
        adjacency[adjbase + u] = (j == i) ? ((o == 0) ? 1.f : 0.f) : po;
        if (j != i) {
            const int jj = j - (j > i ? 1 : 0);
            bond_logits[bondbase + (size_t)jj * 5 + o] = lo;
        }
    }
}

// ---------------------------------------------------------------------------
extern "C" void kernel_launch(void* const* d_in, const int* in_sizes, int n_in,
                              void* d_out, int out_size, void* d_ws, size_t ws_size,
                              hipStream_t stream)
{
    (void)in_sizes; (void)n_in; (void)out_size; (void)ws_size;
    const float* h   = (const float*)d_in[0];
    const float* pos = (const float*)d_in[1];
    // d_in[2] edge_index, d_in[3] batch: unused by the reference forward
    const float* aW1 = (const float*)d_in[4];
    const float* ab1 = (const float*)d_in[5];
    const float* ag  = (const float*)d_in[6];
    const float* abn = (const float*)d_in[7];
    const float* aW2 = (const float*)d_in[8];
    const float* ab2 = (const float*)d_in[9];
    const float* aW3 = (const float*)d_in[10];
    const float* ab3 = (const float*)d_in[11];
    const float* vW1 = (const float*)d_in[12];
    const float* vb1 = (const float*)d_in[13];
    const float* vg  = (const float*)d_in[14];
    const float* vbn = (const float*)d_in[15];
    const float* vW2 = (const float*)d_in[16];
    const float* vb2 = (const float*)d_in[17];
    const float* vW3 = (const float*)d_in[18];
    const float* vb3 = (const float*)d_in[19];
    const float* bW1 = (const float*)d_in[20];
    const float* bb1 = (const float*)d_in[21];
    const float* bg  = (const float*)d_in[22];
    const float* bbn = (const float*)d_in[23];
    const float* bW2 = (const float*)d_in[24];
    const float* bb2 = (const float*)d_in[25];
    const float* bW3 = (const float*)d_in[26];
    const float* bb3 = (const float*)d_in[27];
    const float* mv  = (const float*)d_in[28];
    const float* cr  = (const float*)d_in[29];

    float* out = (float*)d_out;
    float* atom_logits = out + OFF_ATOM;
    float* bond_logits = out + OFF_BOND;
    float* valmat      = out + OFF_VALM;
    float* adjacency   = out + OFF_ADJ;

    float* ws    = (float*)d_ws;
    float* ma    = ws;                  // 4096
    float* rad   = ws + 4096;           // 4096
    float* val   = ws + 8192;           // 4096
    float* Pp    = ws + 12288;          // 1048576
    float* Qq    = ws + 1060864;        // 1048576
    short* W2f   = (short*)(ws + 2109440);   // 32768 bf16 (16384 floats)
    short* W3f   = (short*)(ws + 2125824);   // 2048 bf16 (1024 floats)

    k_pq<<<512, 256, 0, stream>>>(h, bW1, bb1, bW2, bW3, Pp, Qq, W2f, W3f);
    k_av<<<512, 256, 0, stream>>>(h, aW1, ab1, ag, abn, aW2, ab2, aW3, ab3,
                                  mv, cr, vW1, vb1, vg, vbn, vW2, vb2, vW3, vb3,
                                  atom_logits, ma, rad, val);
    k_valmat<<<4096, 256, 0, stream>>>(val, ma, valmat);
    k_bond<<<4096, 256, 0, stream>>>(pos, rad, Pp, Qq, bW1, bg, bbn,
                                     bb2, W2f, W3f, bb3, bond_logits, adjacency);
}

// Round 5
// 333.963 us; speedup vs baseline: 1.2242x; 1.2242x over previous
//
#include <hip/hip_runtime.h>
#include <math.h>

// Problem constants
#define NN   4096   // total nodes
#define HH   256    // hidden
#define NEC  119    // element classes
#define NBC  5      // bond classes
#define NMOL 64     // molecules
#define MAT  64     // atoms per molecule

// output layout (float elements)
#define OFF_ATOM   0
#define SZ_ATOM    (4096*119)          // 487424
#define OFF_BOND   487424
#define SZ_BOND    (258048*5)          // 1290240
#define OFF_VALM   (487424+1290240)    // 1777664
#define SZ_VALM    (4096*4096)         // 16777216
#define OFF_ADJ    (1777664+16777216)  // 18554880

typedef short  bf16x8 __attribute__((ext_vector_type(8)));
typedef float  f32x4  __attribute__((ext_vector_type(4)));

// Branchless gelu: 0.5x(1+erf(x/sqrt2)), erf via A&S 7.1.26 (|err|<=1.5e-7).
__device__ __forceinline__ float gelu_f(float x) {
    float z = fabsf(x) * 0.70710678118654752f;
    float t = __builtin_amdgcn_rcpf(fmaf(0.3275911f, z, 1.0f));
    float p = t * fmaf(t, fmaf(t, fmaf(t, fmaf(t, 1.061405429f, -1.453152027f),
                                       1.421413741f), -0.284496736f), 0.254829592f);
    float er = fmaf(-p, __expf(-z * z), 1.0f);   // erf(|x|/sqrt2)
    float s = copysignf(er, x);
    return 0.5f * x * (1.f + s);
}
__device__ __forceinline__ unsigned short f2bf(float x) {
    unsigned int u = __float_as_uint(x);
    unsigned int r = (u + 0x7fffu + ((u >> 16) & 1u)) >> 16;
    return (unsigned short)r;
}

// ---------------------------------------------------------------------------
// K1 (k_front): blocks 0..511  = fused atom+valency MLP (8 nodes/block)
//               blocks 512..1023 = P/Q projection (8 nodes/block)
//               (pq blocks 0..127 also pre-pack bW2/bW3 MFMA B-fragments)
// Fused into one kernel so both latency-bound halves co-reside (4 blocks/CU).
// ---------------------------------------------------------------------------
__global__ __launch_bounds__(256) void k_front(
    const float* __restrict__ h,
    const float* __restrict__ aW1, const float* __restrict__ ab1,
    const float* __restrict__ ag,  const float* __restrict__ abn,
    const float* __restrict__ aW2, const float* __restrict__ ab2,
    const float* __restrict__ aW3, const float* __restrict__ ab3,
    const float* __restrict__ maxv, const float* __restrict__ covr,
    const float* __restrict__ vW1, const float* __restrict__ vb1,
    const float* __restrict__ vg,  const float* __restrict__ vbn,
    const float* __restrict__ vW2, const float* __restrict__ vb2,
    const float* __restrict__ vW3, const float* __restrict__ vb3,
    const float* __restrict__ bW1, const float* __restrict__ bb1,
    const float* __restrict__ bW2, const float* __restrict__ bW3,
    float* __restrict__ logits_out,
    float* __restrict__ ma, float* __restrict__ rad, float* __restrict__ val,
    float* __restrict__ P, float* __restrict__ Q,
    short* __restrict__ W2f, short* __restrict__ W3f)
{
    // union'd LDS: av path uses all 7056 floats; pq path uses first 2048
    __shared__ float smem[7056];
    float (*hs)[376]   = (float(*)[376])smem;            // 3008
    float (*z1)[256]   = (float(*)[256])(smem + 3008);   // 2048
    float (*z2)[128]   = (float(*)[128])(smem + 5056);   // 1024
    float (*llog)[120] = (float(*)[120])(smem + 6080);   //  960
    float (*redbuf)[2] = (float(*)[2])  (smem + 7040);   //   16

    const int t  = threadIdx.x;
    const int wv = t >> 6, ln = t & 63;

    if (blockIdx.x >= 512) {
        // =================== PQ path ===================
        const int pb = blockIdx.x - 512;
        const int n0 = pb * 8;

        if (pb < 128) {
            const int id = pb * 256 + t;
            {   // W2f: [256,128] -> B-fragments (32768 entries)
                const int e = id & 7, l = (id >> 3) & 63, ks = (id >> 9) & 7, ct = (id >> 12) & 7;
                const int k = ks * 32 + (l >> 4) * 8 + e;
                const int col = ct * 16 + (l & 15);
                W2f[id] = (short)f2bf(bW2[k * 128 + col]);
            }
            if (id < 2048) {
                const int e = id & 7, l = (id >> 3) & 63, ks = id >> 9;
                const int k = ks * 32 + (l >> 4) * 8 + e;
                const int col = l & 15;
                W3f[id] = (col < NBC) ? (short)f2bf(bW3[k * NBC + col]) : (short)0;
            }
        }

        float (*hq)[256] = (float(*)[256])smem;
        for (int idx = t; idx < 8 * 256; idx += 256)
            ((float*)hq)[idx] = h[(size_t)n0 * 256 + idx];
        __syncthreads();

        const int c = t;
        float accp[8], accq[8];
        float b1 = bb1[c];
        #pragma unroll
        for (int r = 0; r < 8; ++r) { accp[r] = b1; accq[r] = 0.f; }
        for (int k4 = 0; k4 < 64; ++k4) {
            const int k = k4 * 4;
            float p0 = bW1[(k + 0) * 256 + c];
            float p1 = bW1[(k + 1) * 256 + c];
            float p2 = bW1[(k + 2) * 256 + c];
            float p3 = bW1[(k + 3) * 256 + c];
            float q0 = bW1[(256 + k + 0) * 256 + c];
            float q1 = bW1[(256 + k + 1) * 256 + c];
            float q2 = bW1[(256 + k + 2) * 256 + c];
            float q3 = bW1[(256 + k + 3) * 256 + c];
            #pragma unroll
            for (int r = 0; r < 8; ++r) {
                float4 hv = *(const float4*)&hq[r][k];
                accp[r] = fmaf(hv.x, p0, accp[r]);
                accp[r] = fmaf(hv.y, p1, accp[r]);
                accp[r] = fmaf(hv.z, p2, accp[r]);
                accp[r] = fmaf(hv.w, p3, accp[r]);
                accq[r] = fmaf(hv.x, q0, accq[r]);
                accq[r] = fmaf(hv.y, q1, accq[r]);
                accq[r] = fmaf(hv.z, q2, accq[r]);
                accq[r] = fmaf(hv.w, q3, accq[r]);
            }
        }
        #pragma unroll
        for (int r = 0; r < 8; ++r) {
            P[(size_t)(n0 + r) * 256 + c] = accp[r];
            Q[(size_t)(n0 + r) * 256 + c] = accq[r];
        }
        return;
    }

    // =================== AV path ===================
    const int n0 = blockIdx.x * 8;

    for (int idx = t; idx < 8 * 256; idx += 256) {
        int r = idx >> 8, cc = idx & 255;
        hs[r][cc] = h[(size_t)(n0 + r) * 256 + cc];
    }
    if (t < 8) hs[t][375] = 0.f;
    __syncthreads();

    // ---- atom layer1 (256->256): thread owns col c ----
    {
        const int c = t;
        float b1 = ab1[c];
        float acc[8];
        #pragma unroll
        for (int r = 0; r < 8; ++r) acc[r] = b1;
        for (int k4 = 0; k4 < 64; ++k4) {
            const int k = k4 * 4;
            float w0 = aW1[(k + 0) * 256 + c];
            float w1 = aW1[(k + 1) * 256 + c];
            float w2 = aW1[(k + 2) * 256 + c];
            float w3 = aW1[(k + 3) * 256 + c];
            #pragma unroll
            for (int r = 0; r < 8; ++r) {
                float4 hv = *(const float4*)&hs[r][k];
                acc[r] = fmaf(hv.x, w0, acc[r]);
                acc[r] = fmaf(hv.y, w1, acc[r]);
                acc[r] = fmaf(hv.z, w2, acc[r]);
                acc[r] = fmaf(hv.w, w3, acc[r]);
            }
        }
        #pragma unroll
        for (int r = 0; r < 8; ++r) z1[r][c] = gelu_f(acc[r]);
    }
    __syncthreads();

    // ---- atom LN stats: wave wv owns rows wv*2, wv*2+1 ----
    for (int rr = 0; rr < 2; ++rr) {
        const int r = wv * 2 + rr;
        float s = 0.f, s2 = 0.f;
        #pragma unroll
        for (int q = 0; q < 4; ++q) {
            float v = z1[r][ln + q * 64];
            s += v; s2 = fmaf(v, v, s2);
        }
        #pragma unroll
        for (int m = 32; m >= 1; m >>= 1) {
            s  += __shfl_xor(s,  m, 64);
            s2 += __shfl_xor(s2, m, 64);
        }
        if (ln == 0) {
            float mu  = s * (1.f / 256.f);
            float var = s2 * (1.f / 256.f) - mu * mu;
            redbuf[r][0] = mu;
            redbuf[r][1] = rsqrtf(var + 1e-5f);
        }
    }
    __syncthreads();
    {
        const int c = t;
        float g = ag[c], b = abn[c];
        #pragma unroll
        for (int r = 0; r < 8; ++r)
            z1[r][c] = (z1[r][c] - redbuf[r][0]) * redbuf[r][1] * g + b;
    }
    __syncthreads();

    // ---- atom layer2 (256->128), k-split halves ----
    {
        const int c2 = t & 127, kh = t >> 7;
        float acc2[8];
        #pragma unroll
        for (int r = 0; r < 8; ++r) acc2[r] = 0.f;
        const int kb = kh * 128;
        for (int k4 = 0; k4 < 32; ++k4) {
            const int k = kb + k4 * 4;
            float w0 = aW2[(k + 0) * 128 + c2];
            float w1 = aW2[(k + 1) * 128 + c2];
            float w2 = aW2[(k + 2) * 128 + c2];
            float w3 = aW2[(k + 3) * 128 + c2];
            #pragma unroll
            for (int r = 0; r < 8; ++r) {
                float4 zv = *(const float4*)&z1[r][k];
                acc2[r] = fmaf(zv.x, w0, acc2[r]);
                acc2[r] = fmaf(zv.y, w1, acc2[r]);
                acc2[r] = fmaf(zv.z, w2, acc2[r]);
                acc2[r] = fmaf(zv.w, w3, acc2[r]);
            }
        }
        if (kh == 1) {
            #pragma unroll
            for (int r = 0; r < 8; ++r) z2[r][c2] = acc2[r];
        }
        __syncthreads();
        if (kh == 0) {
            float b2 = ab2[c2];
            #pragma unroll
            for (int r = 0; r < 8; ++r)
                z2[r][c2] = gelu_f(acc2[r] + z2[r][c2] + b2);
        }
    }
    __syncthreads();

    // ---- atom layer3 (128->119) ----
    if (t < NEC) {
        const int c = t;
        float b3 = ab3[c];
        float acc3[8];
        #pragma unroll
        for (int r = 0; r < 8; ++r) acc3[r] = b3;
        for (int k4 = 0; k4 < 32; ++k4) {
            const int k = k4 * 4;
            float w0 = aW3[(k + 0) * NEC + c];
            float w1 = aW3[(k + 1) * NEC + c];
            float w2 = aW3[(k + 2) * NEC + c];
            float w3 = aW3[(k + 3) * NEC + c];
            #pragma unroll
            for (int r = 0; r < 8; ++r) {
                float4 zv = *(const float4*)&z2[r][k];
                acc3[r] = fmaf(zv.x, w0, acc3[r]);
                acc3[r] = fmaf(zv.y, w1, acc3[r]);
                acc3[r] = fmaf(zv.z, w2, acc3[r]);
                acc3[r] = fmaf(zv.w, w3, acc3[r]);
            }
        }
        #pragma unroll
        for (int r = 0; r < 8; ++r) {
            llog[r][c] = acc3[r];
            logits_out[(size_t)(n0 + r) * NEC + c] = acc3[r];
        }
    }
    __syncthreads();

    // ---- atom softmax + argmax; probs -> hs[r][256+cc] ----
    for (int rr = 0; rr < 2; ++rr) {
        const int r = wv * 2 + rr;
        float v1 = llog[r][ln];
        float v2 = (ln + 64 < NEC) ? llog[r][ln + 64] : -1e30f;
        float mx; int mi;
        if (v2 > v1) { mx = v2; mi = ln + 64; } else { mx = v1; mi = ln; }
        #pragma unroll
        for (int m = 32; m >= 1; m >>= 1) {
            float ov = __shfl_xor(mx, m, 64);
            int   oi = __shfl_xor(mi, m, 64);
            if (ov > mx || (ov == mx && oi < mi)) { mx = ov; mi = oi; }
        }
        float e1 = __expf(v1 - mx);
        float e2 = (ln + 64 < NEC) ? __expf(v2 - mx) : 0.f;
        float s = e1 + e2;
        #pragma unroll
        for (int m = 32; m >= 1; m >>= 1) s += __shfl_xor(s, m, 64);
        float inv = __builtin_amdgcn_rcpf(s);
        hs[r][256 + ln] = e1 * inv;
        if (ln + 64 < NEC) hs[r][256 + ln + 64] = e2 * inv;
        if (ln == 0) {
            ma[n0 + r]  = maxv[mi];
            rad[n0 + r] = covr[mi];
        }
    }
    __syncthreads();

    // ---- valency layer1 (375->256): 93 full quads + 3-tail ----
    {
        const int c = t;
        float b1 = vb1[c];
        float acc[8];
        #pragma unroll
        for (int r = 0; r < 8; ++r) acc[r] = b1;
        for (int k4 = 0; k4 < 93; ++k4) {
            const int k = k4 * 4;
            float w0 = vW1[(k + 0) * 256 + c];
            float w1 = vW1[(k + 1) * 256 + c];
            float w2 = vW1[(k + 2) * 256 + c];
            float w3 = vW1[(k + 3) * 256 + c];
            #pragma unroll
            for (int r = 0; r < 8; ++r) {
                float4 hv = *(const float4*)&hs[r][k];
                acc[r] = fmaf(hv.x, w0, acc[r]);
                acc[r] = fmaf(hv.y, w1, acc[r]);
                acc[r] = fmaf(hv.z, w2, acc[r]);
                acc[r] = fmaf(hv.w, w3, acc[r]);
            }
        }
        {
            float w0 = vW1[372 * 256 + c];
            float w1 = vW1[373 * 256 + c];
            float w2 = vW1[374 * 256 + c];
            #pragma unroll
            for (int r = 0; r < 8; ++r) {
                acc[r] = fmaf(hs[r][372], w0, acc[r]);
                acc[r] = fmaf(hs[r][373], w1, acc[r]);
                acc[r] = fmaf(hs[r][374], w2, acc[r]);
            }
        }
        #pragma unroll
        for (int r = 0; r < 8; ++r) z1[r][c] = gelu_f(acc[r]);
    }
    __syncthreads();

    // ---- valency LN ----
    for (int rr = 0; rr < 2; ++rr) {
        const int r = wv * 2 + rr;
        float s = 0.f, s2 = 0.f;
        #pragma unroll
        for (int q = 0; q < 4; ++q) {
            float v = z1[r][ln + q * 64];
            s += v; s2 = fmaf(v, v, s2);
        }
        #pragma unroll
        for (int m = 32; m >= 1; m >>= 1) {
            s  += __shfl_xor(s,  m, 64);
            s2 += __shfl_xor(s2, m, 64);
        }
        if (ln == 0) {
            float mu  = s * (1.f / 256.f);
            float var = s2 * (1.f / 256.f) - mu * mu;
            redbuf[r][0] = mu;
            redbuf[r][1] = rsqrtf(var + 1e-5f);
        }
    }
    __syncthreads();
    {
        const int c = t;
        float g = vg[c], b = vbn[c];
        #pragma unroll
        for (int r = 0; r < 8; ++r)
            z1[r][c] = (z1[r][c] - redbuf[r][0]) * redbuf[r][1] * g + b;
    }
    __syncthreads();

    // ---- valency layer2 (256->128) ----
    {
        const int c2 = t & 127, kh = t >> 7;
        float acc2[8];
        #pragma unroll
        for (int r = 0; r < 8; ++r) acc2[r] = 0.f;
        const int kb = kh * 128;
        for (int k4 = 0; k4 < 32; ++k4) {
            const int k = kb + k4 * 4;
            float w0 = vW2[(k + 0) * 128 + c2];
            float w1 = vW2[(k + 1) * 128 + c2];
            float w2 = vW2[(k + 2) * 128 + c2];
            float w3 = vW2[(k + 3) * 128 + c2];
            #pragma unroll
            for (int r = 0; r < 8; ++r) {
                float4 zv = *(const float4*)&z1[r][k];
                acc2[r] = fmaf(zv.x, w0, acc2[r]);
                acc2[r] = fmaf(zv.y, w1, acc2[r]);
                acc2[r] = fmaf(zv.z, w2, acc2[r]);
                acc2[r] = fmaf(zv.w, w3, acc2[r]);
            }
        }
        if (kh == 1) {
            #pragma unroll
            for (int r = 0; r < 8; ++r) z2[r][c2] = acc2[r];
        }
        __syncthreads();
        if (kh == 0) {
            float b2 = vb2[c2];
            #pragma unroll
            for (int r = 0; r < 8; ++r)
                z2[r][c2] = gelu_f(acc2[r] + z2[r][c2] + b2);
        }
    }
    __syncthreads();

    // ---- valency layer3 (128->1) + softplus ----
    for (int rr = 0; rr < 2; ++rr) {
        const int r = wv * 2 + rr;
        float p = fmaf(z2[r][ln], vW3[ln], z2[r][ln + 64] * vW3[ln + 64]);
        #pragma unroll
        for (int m = 32; m >= 1; m >>= 1) p += __shfl_xor(p, m, 64);
        if (ln == 0) {
            float x = p + vb3[0];
            val[n0 + r] = (x > 15.f) ? x : log1pf(expf(x));
        }
    }
}

// ---------------------------------------------------------------------------
// K2 (k_back): blocks 0..4095 = bond MLP per (b,i); blocks 4096..4607 =
//   valency_constrained rows (8 rows/block) — pure-BW work hides under bond.
// ---------------------------------------------------------------------------
__global__ __launch_bounds__(256) void k_back(
    const float* __restrict__ pos, const float* __restrict__ rad,
    const float* __restrict__ P, const float* __restrict__ Q,
    const float* __restrict__ bW1,
    const float* __restrict__ bg, const float* __restrict__ bbn,
    const float* __restrict__ bb2,
    const short* __restrict__ W2f, const short* __restrict__ W3f,
    const float* __restrict__ bb3,
    const float* __restrict__ val, const float* __restrict__ ma,
    float* __restrict__ bond_logits, float* __restrict__ adjacency,
    float* __restrict__ valmat)
{
    __shared__ float posr[64][4];
    __shared__ float bb2s[128];
    __shared__ unsigned short Xs[64 * 256];   // bf16; 16B-chunk XOR swizzle by (row&7)
    __shared__ float Ls[64][5];
    unsigned short* Ys = Xs;                  // alias: Xs dead after Phase B MFMAs

    const int t  = threadIdx.x;

    if (blockIdx.x >= 4096) {
        // =================== valmat path ===================
        const int i0 = (blockIdx.x - 4096) * 8;
        const float4* v4 = (const float4*)val;
        for (int rr = 0; rr < 8; ++rr) {
            const int i = i0 + rr;
            const float mi = ma[i];
            float4* o4 = (float4*)(valmat + (size_t)i * 4096);
            for (int j = t; j < 1024; j += 256) {
                float4 v = v4[j];
                float4 r;
                r.x = fminf(v.x, mi); r.y = fminf(v.y, mi);
                r.z = fminf(v.z, mi); r.w = fminf(v.w, mi);
                o4[j] = r;
            }
        }
        return;
    }

    // =================== bond path ===================
    const int bi = blockIdx.x;
    const int b  = bi >> 6, i = bi & 63;
    const int wv = t >> 6, ln = t & 63;
    const int node0 = b * 64;

    if (t < 64) {
        int n = node0 + t;
        posr[t][0] = pos[n * 3 + 0];
        posr[t][1] = pos[n * 3 + 1];
        posr[t][2] = pos[n * 3 + 2];
        posr[t][3] = rad[n];
    }
    if (t >= 128 && t < 256) bb2s[t - 128] = bb2[t - 128];
    __syncthreads();

    // ---- Phase A: layer1 + LN, wave wv owns j in [wv*16, wv*16+16) ----
    {
        const int c0 = ln * 4;                    // lane owns channels c0..c0+3
        const size_t nodei = (size_t)(node0 + i);
        float4 Pi  = *(const float4*)(P + nodei * 256 + c0);
        float4 w0  = *(const float4*)(bW1 + (size_t)512 * 256 + c0);
        float4 w1  = *(const float4*)(bW1 + (size_t)513 * 256 + c0);
        float4 w2  = *(const float4*)(bW1 + (size_t)514 * 256 + c0);
        float4 w3  = *(const float4*)(bW1 + (size_t)515 * 256 + c0);
        float4 gam = *(const float4*)(bg  + c0);
        float4 bet = *(const float4*)(bbn + c0);
        const float xi = posr[i][0], yi = posr[i][1], zi = posr[i][2], ri = posr[i][3];

        #pragma unroll 2
        for (int jj = 0; jj < 16; ++jj) {
            const int j = wv * 16 + jj;
            float dx = xi - posr[j][0];
            float dy = yi - posr[j][1];
            float dz = zi - posr[j][2];
            float dist = sqrtf(fmaf(dx, dx, fmaf(dy, dy, dz * dz)));
            float expd = ri + posr[j][3];
            float ratio = dist * __builtin_amdgcn_rcpf(expd);
            float close = (dist < 3.f) ? 1.f : 0.f;
            float4 qv = *(const float4*)(Q + (size_t)(node0 + j) * 256 + c0);

            float g0 = Pi.x + qv.x;
            g0 = fmaf(w0.x, dist, g0); g0 = fmaf(w1.x, expd, g0);
            g0 = fmaf(w2.x, ratio, g0); g0 = fmaf(w3.x, close, g0);
            float g1 = Pi.y + qv.y;
            g1 = fmaf(w0.y, dist, g1); g1 = fmaf(w1.y, expd, g1);
            g1 = fmaf(w2.y, ratio, g1); g1 = fmaf(w3.y, close, g1);
            float g2 = Pi.z + qv.z;
            g2 = fmaf(w0.z, dist, g2); g2 = fmaf(w1.z, expd, g2);
            g2 = fmaf(w2.z, ratio, g2); g2 = fmaf(w3.z, close, g2);
            float g3 = Pi.w + qv.w;
            g3 = fmaf(w0.w, dist, g3); g3 = fmaf(w1.w, expd, g3);
            g3 = fmaf(w2.w, ratio, g3); g3 = fmaf(w3.w, close, g3);
            g0 = gelu_f(g0); g1 = gelu_f(g1); g2 = gelu_f(g2); g3 = gelu_f(g3);

            float s  = g0 + g1 + g2 + g3;
            float s2 = fmaf(g0, g0, fmaf(g1, g1, fmaf(g2, g2, g3 * g3)));
            #pragma unroll
            for (int m = 32; m >= 1; m >>= 1) {
                s  += __shfl_xor(s,  m, 64);
                s2 += __shfl_xor(s2, m, 64);
            }
            float mu   = s * (1.f / 256.f);
            float rstd = rsqrtf(s2 * (1.f / 256.f) - mu * mu + 1e-5f);

            ushort4 u;
            u.x = f2bf((g0 - mu) * rstd * gam.x + bet.x);
            u.y = f2bf((g1 - mu) * rstd * gam.y + bet.y);
            u.z = f2bf((g2 - mu) * rstd * gam.z + bet.z);
            u.w = f2bf((g3 - mu) * rstd * gam.w + bet.w);
            // swizzled write: chunk = c0/8, chunk' = chunk ^ (j&7)
            const int chunk = ln >> 1;
            const int off   = j * 512 + ((chunk ^ (j & 7)) << 4) + ((ln & 1) << 3);
            *(ushort4*)((char*)Xs + off) = u;
        }
    }
    __syncthreads();

    // ---- Phase B: Y = Xs @ W2f via MFMA; wave wv owns cols [wv*32, wv*32+32) ----
    {
        const int lrow = ln & 15, lk = ln >> 4;
        f32x4 acc[4][2];
        #pragma unroll
        for (int jt = 0; jt < 4; ++jt)
            #pragma unroll
            for (int c2 = 0; c2 < 2; ++c2)
                acc[jt][c2] = (f32x4){0.f, 0.f, 0.f, 0.f};

        #pragma unroll
        for (int ks = 0; ks < 8; ++ks) {
            bf16x8 bfr0 = *(const bf16x8*)(W2f + (((size_t)(2 * wv + 0) * 8 + ks) * 64 + ln) * 8);
            bf16x8 bfr1 = *(const bf16x8*)(W2f + (((size_t)(2 * wv + 1) * 8 + ks) * 64 + ln) * 8);
            #pragma unroll
            for (int jt = 0; jt < 4; ++jt) {
                const int row   = jt * 16 + lrow;
                const int chunk = ks * 4 + lk;
                const int off   = row * 512 + ((chunk ^ (row & 7)) << 4);
                bf16x8 afr = *(const bf16x8*)((char*)Xs + off);
                acc[jt][0] = __builtin_amdgcn_mfma_f32_16x16x32_bf16(afr, bfr0, acc[jt][0], 0, 0, 0);
                acc[jt][1] = __builtin_amdgcn_mfma_f32_16x16x32_bf16(afr, bfr1, acc[jt][1], 0, 0, 0);
            }
        }
        __syncthreads();   // all waves done reading Xs before Ys (alias) writes

        // epilogue: gelu(Y + bb2) -> Ys (bf16, swizzled)
        #pragma unroll
        for (int jt = 0; jt < 4; ++jt) {
            #pragma unroll
            for (int c2 = 0; c2 < 2; ++c2) {
                const int col = (2 * wv + c2) * 16 + lrow;
                const float bb = bb2s[col];
                #pragma unroll
                for (int r = 0; r < 4; ++r) {
                    const int row = jt * 16 + lk * 4 + r;
                    float y = gelu_f(acc[jt][c2][r] + bb);
                    const int chunk = col >> 3;
                    const int off = row * 256 + ((chunk ^ (row & 7)) << 4) + ((col & 7) << 1);
                    *(unsigned short*)((char*)Ys + off) = f2bf(y);
                }
            }
        }
    }
    __syncthreads();

    // ---- Phase B2: L = Ys @ W3f (pad 16 cols); wave wv owns j-tile wv ----
    {
        const int lrow = ln & 15, lk = ln >> 4;
        f32x4 acc3 = (f32x4){0.f, 0.f, 0.f, 0.f};
        #pragma unroll
        for (int ks = 0; ks < 4; ++ks) {
            bf16x8 bfr = *(const bf16x8*)(W3f + ((size_t)(ks * 64 + ln)) * 8);
            const int row   = wv * 16 + lrow;
            const int chunk = ks * 4 + lk;
            const int off   = row * 256 + ((chunk ^ (row & 7)) << 4);
            bf16x8 afr = *(const bf16x8*)((char*)Ys + off);
            acc3 = __builtin_amdgcn_mfma_f32_16x16x32_bf16(afr, bfr, acc3, 0, 0, 0);
        }
        if (lrow < NBC) {
            #pragma unroll
            for (int r = 0; r < 4; ++r)
                Ls[wv * 16 + lk * 4 + r][lrow] = acc3[r];
        }
    }
    __syncthreads();

    // ---- write adjacency (softmax5, diag=e0) + bond_logits (off-diag) ----
    const size_t adjbase  = (size_t)bi * 64 * 5;
    const size_t bondbase = ((size_t)b * 4032 + (size_t)i * 63) * 5;
    const float b30 = bb3[0], b31 = bb3[1], b32 = bb3[2], b33 = bb3[3], b34 = bb3[4];
    for (int u = t; u < 320; u += 256) {
        const int j = u / 5, o = u - (u / 5) * 5;
        float l0 = Ls[j][0] + b30, l1 = Ls[j][1] + b31, l2 = Ls[j][2] + b32;
        float l3 = Ls[j][3] + b33, l4 = Ls[j][4] + b34;
        float mx = fmaxf(fmaxf(fmaxf(l0, l1), fmaxf(l2, l3)), l4);
        float e0 = __expf(l0 - mx), e1 = __expf(l1 - mx), e2 = __expf(l2 - mx);
        float e3 = __expf(l3 - mx), e4 = __expf(l4 - mx);
        float inv = __builtin_amdgcn_rcpf(e0 + e1 + e2 + e3 + e4);
        float lo = (o == 0) ? l0 : (o == 1) ? l1 : (o == 2) ? l2 : (o == 3) ? l3 : l4;
        float po = ((o == 0) ? e0 : (o == 1) ? e1 : (o == 2) ? e2 : (o == 3) ? e3 : e4) * inv;
        adjacency[adjbase + u] = (j == i) ? ((o == 0) ? 1.f : 0.f) : po;
        if (j != i) {
            const int jj = j - (j > i ? 1 : 0);
            bond_logits[bondbase + (size_t)jj * 5 + o] = lo;
        }
    }
}

// ---------------------------------------------------------------------------
extern "C" void kernel_launch(void* const* d_in, const int* in_sizes, int n_in,
                              void* d_out, int out_size, void* d_ws, size_t ws_size,
                              hipStream_t stream)
{
    (void)in_sizes; (void)n_in; (void)out_size; (void)ws_size;
    const float* h   = (const float*)d_in[0];
    const float* pos = (const float*)d_in[1];
    // d_in[2] edge_index, d_in[3] batch: unused by the reference forward
    const float* aW1 = (const float*)d_in[4];
    const float* ab1 = (const float*)d_in[5];
    const float* ag  = (const float*)d_in[6];
    const float* abn = (const float*)d_in[7];
    const float* aW2 = (const float*)d_in[8];
    const float* ab2 = (const float*)d_in[9];
    const float* aW3 = (const float*)d_in[10];
    const float* ab3 = (const float*)d_in[11];
    const float* vW1 = (const float*)d_in[12];
    const float* vb1 = (const float*)d_in[13];
    const float* vg  = (const float*)d_in[14];
    const float* vbn = (const float*)d_in[15];
    const float* vW2 = (const float*)d_in[16];
    const float* vb2 = (const float*)d_in[17];
    const float* vW3 = (const float*)d_in[18];
    const float* vb3 = (const float*)d_in[19];
    const float* bW1 = (const float*)d_in[20];
    const float* bb1 = (const float*)d_in[21];
    const float* bg  = (const float*)d_in[22];
    const float* bbn = (const float*)d_in[23];
    const float* bW2 = (const float*)d_in[24];
    const float* bb2 = (const float*)d_in[25];
    const float* bW3 = (const float*)d_in[26];
    const float* bb3 = (const float*)d_in[27];
    const float* mv  = (const float*)d_in[28];
    const float* cr  = (const float*)d_in[29];

    float* out = (float*)d_out;
    float* atom_logits = out + OFF_ATOM;
    float* bond_logits = out + OFF_BOND;
    float* valmat      = out + OFF_VALM;
    float* adjacency   = out + OFF_ADJ;

    float* ws    = (float*)d_ws;
    float* ma    = ws;                  // 4096
    float* rad   = ws + 4096;           // 4096
    float* val   = ws + 8192;           // 4096
    float* Pp    = ws + 12288;          // 1048576
    float* Qq    = ws + 1060864;        // 1048576
    short* W2f   = (short*)(ws + 2109440);   // 32768 bf16 (16384 floats)
    short* W3f   = (short*)(ws + 2125824);   // 2048 bf16 (1024 floats)

    k_front<<<1024, 256, 0, stream>>>(h,
        aW1, ab1, ag, abn, aW2, ab2, aW3, ab3, mv, cr,
        vW1, vb1, vg, vbn, vW2, vb2, vW3, vb3,
        bW1, bb1, bW2, bW3,
        atom_logits, ma, rad, val, Pp, Qq, W2f, W3f);
    k_back<<<4608, 256, 0, stream>>>(pos, rad, Pp, Qq, bW1, bg, bbn,
                                     bb2, W2f, W3f, bb3, val, ma,
                                     bond_logits, adjacency, valmat);
}